// Round 3
// baseline (131.347 us; speedup 1.0000x reference)
//
#include <hip/hip_runtime.h>
#include <math.h>

// TDVP_V2: BATCH=16384 chains, N=64 sites, D=4, DIN=DOUT=2.
// v3: segmented parallel scan. Thread = (batch, segment of 4 sites).
// Block: 256 threads = 16 batches x 16 segments. Grid: 1024 blocks.
//   Phase 1 : per-thread segment product P_s = M[4s]..M[4s+3] (normalized) -> LDS
//   Phase 2a: lanes s==0/s==1 do 15-step vector scans over P -> prefix/suffix
//             vectors per segment (direction only; scale cancels in H-norm)
//   Phase 2b: per-thread 4-site walks rebuild vL/Ar per site and fuse the
//             epilogue H = vl.B.ar, norm/nan/relu, y = H.xn. Full fp32.
// LDS: sP 16*65 float4 (padded stride 65 to dodge bank conflicts) +
//      sPre/sSuf 16*16 float4 each = 24.8 KB.

#define EPS 1e-6f
#define BPB 16   // batches per block
#define SEG 16   // segments per chain (4 sites each)

__device__ __forceinline__ void build_M(const float* __restrict__ A, int n,
                                        float xn0, float xn1, float* Mm) {
    const float4* Aq = (const float4*)A + (size_t)n * 8;
    float a[32];
    #pragma unroll
    for (int t = 0; t < 8; ++t) {
        float4 q = Aq[t];
        a[4*t] = q.x; a[4*t+1] = q.y; a[4*t+2] = q.z; a[4*t+3] = q.w;
    }
    #pragma unroll
    for (int e = 0; e < 16; ++e)
        Mm[e] = fmaf(xn1, a[2*e+1], xn0 * a[2*e]);
}

__global__ __launch_bounds__(256)
void tdvp_kernel(const float* __restrict__ x,
                 const float* __restrict__ A,
                 const float* __restrict__ Bw,
                 const float* __restrict__ scale,
                 float* __restrict__ y)
{
    __shared__ float4 sP[BPB * 65];        // [b*65 + s*4 + r], padded stride
    __shared__ float4 sPre[BPB * SEG];     // prefix vec per (b, seg)
    __shared__ float4 sSuf[BPB * SEG];     // suffix vec per (b, seg)

    const int tid   = threadIdx.x;
    const int b     = tid >> 4;            // 0..15  batch-in-block
    const int s     = tid & 15;            // 0..15  segment
    const int batch = blockIdx.x * BPB + b;
    const int n0    = s * 4;

    const float* xb = x + (size_t)batch * 128;
    float*       yb = y + (size_t)batch * 128;

    // x for this thread's 4 sites -> normalized xn
    const float4 xq0 = ((const float4*)xb)[s * 2];
    const float4 xq1 = ((const float4*)xb)[s * 2 + 1];
    float xn[4][2];
    {
        const float px[8] = {xq0.x, xq0.y, xq0.z, xq0.w,
                             xq1.x, xq1.y, xq1.z, xq1.w};
        #pragma unroll
        for (int k = 0; k < 4; ++k) {
            const float xx = px[2*k], xy = px[2*k+1];
            const float inr = 1.f / sqrtf(xx * xx + xy * xy);
            xn[k][0] = xx * inr; xn[k][1] = xy * inr;
        }
    }

    // ---------------- phase 1: segment product P = M0.M1.M2.M3 --------------
    float P[16];
    build_M(A, n0, xn[0][0], xn[0][1], P);
    #pragma unroll
    for (int k = 1; k < 4; ++k) {
        float Mm[16];
        build_M(A, n0 + k, xn[k][0], xn[k][1], Mm);
        float Pn[16];
        #pragma unroll
        for (int i = 0; i < 4; ++i) {
            #pragma unroll
            for (int j = 0; j < 4; ++j) {
                float acc = P[i*4] * Mm[j];
                acc = fmaf(P[i*4+1], Mm[4+j],  acc);
                acc = fmaf(P[i*4+2], Mm[8+j],  acc);
                acc = fmaf(P[i*4+3], Mm[12+j], acc);
                Pn[i*4+j] = acc;
            }
        }
        #pragma unroll
        for (int e = 0; e < 16; ++e) P[e] = Pn[e];
    }
    {
        float ss = 0.f;
        #pragma unroll
        for (int e = 0; e < 16; ++e) ss = fmaf(P[e], P[e], ss);
        const float rn = 1.f / (sqrtf(ss) + 1e-30f);
        #pragma unroll
        for (int r = 0; r < 4; ++r)
            sP[b*65 + s*4 + r] = make_float4(P[4*r]*rn, P[4*r+1]*rn,
                                             P[4*r+2]*rn, P[4*r+3]*rn);
    }
    __syncthreads();

    // ---------------- phase 2a: vector scans over segment products ----------
    if (s == 0) {
        // prefix: pre[t] = norm(e0^T P_0 .. P_{t-1})
        float v0 = 1.f, v1 = 0.f, v2 = 0.f, v3 = 0.f;
        sPre[b*16] = make_float4(1.f, 0.f, 0.f, 0.f);
        #pragma unroll 1
        for (int t = 1; t < 16; ++t) {
            const float4 r0 = sP[b*65 + (t-1)*4 + 0];
            const float4 r1 = sP[b*65 + (t-1)*4 + 1];
            const float4 r2 = sP[b*65 + (t-1)*4 + 2];
            const float4 r3 = sP[b*65 + (t-1)*4 + 3];
            const float w0 = v0*r0.x + v1*r1.x + v2*r2.x + v3*r3.x;
            const float w1 = v0*r0.y + v1*r1.y + v2*r2.y + v3*r3.y;
            const float w2 = v0*r0.z + v1*r1.z + v2*r2.z + v3*r3.z;
            const float w3 = v0*r0.w + v1*r1.w + v2*r2.w + v3*r3.w;
            const float rn = 1.f / (sqrtf(w0*w0 + w1*w1 + w2*w2 + w3*w3) + 1e-30f);
            v0 = w0*rn; v1 = w1*rn; v2 = w2*rn; v3 = w3*rn;
            sPre[b*16 + t] = make_float4(v0, v1, v2, v3);
        }
    } else if (s == 1) {
        // suffix: suf[t] = norm(P_{t+1} .. P_15 e0)
        float u0 = 1.f, u1 = 0.f, u2 = 0.f, u3 = 0.f;
        sSuf[b*16 + 15] = make_float4(1.f, 0.f, 0.f, 0.f);
        #pragma unroll 1
        for (int t = 14; t >= 0; --t) {
            const float4 r0 = sP[b*65 + (t+1)*4 + 0];
            const float4 r1 = sP[b*65 + (t+1)*4 + 1];
            const float4 r2 = sP[b*65 + (t+1)*4 + 2];
            const float4 r3 = sP[b*65 + (t+1)*4 + 3];
            const float w0 = r0.x*u0 + r0.y*u1 + r0.z*u2 + r0.w*u3;
            const float w1 = r1.x*u0 + r1.y*u1 + r1.z*u2 + r1.w*u3;
            const float w2 = r2.x*u0 + r2.y*u1 + r2.z*u2 + r2.w*u3;
            const float w3 = r3.x*u0 + r3.y*u1 + r3.z*u2 + r3.w*u3;
            const float rn = 1.f / (sqrtf(w0*w0 + w1*w1 + w2*w2 + w3*w3) + 1e-30f);
            u0 = w0*rn; u1 = w1*rn; u2 = w2*rn; u3 = w3*rn;
            sSuf[b*16 + t] = make_float4(u0, u1, u2, u3);
        }
    }
    __syncthreads();

    // ---------------- phase 2b: per-site walks + fused epilogue -------------
    // forward: vl_raw[k] = prefix vector before M[n0+k]
    float vl[4][4];
    {
        const float4 pv = sPre[b*16 + s];
        float v0 = pv.x, v1 = pv.y, v2 = pv.z, v3 = pv.w;
        #pragma unroll
        for (int k = 0; k < 4; ++k) {
            vl[k][0] = v0; vl[k][1] = v1; vl[k][2] = v2; vl[k][3] = v3;
            if (k == 3) break;
            float Mm[16];
            build_M(A, n0 + k, xn[k][0], xn[k][1], Mm);
            const float t0 = v0*Mm[0] + v1*Mm[4] + v2*Mm[8]  + v3*Mm[12];
            const float t1 = v0*Mm[1] + v1*Mm[5] + v2*Mm[9]  + v3*Mm[13];
            const float t2 = v0*Mm[2] + v1*Mm[6] + v2*Mm[10] + v3*Mm[14];
            const float t3 = v0*Mm[3] + v1*Mm[7] + v2*Mm[11] + v3*Mm[15];
            v0 = t0; v1 = t1; v2 = t2; v3 = t3;
        }
    }

    const float sc = scale[0];
    const float4 sv = sSuf[b*16 + s];
    float u0 = sv.x, u1 = sv.y, u2 = sv.z, u3 = sv.w;
    float yo[8];

    #pragma unroll
    for (int kk = 3; kk >= 0; --kk) {
        const int n = n0 + kk;

        float arn = 1.f / (sqrtf(u0*u0 + u1*u1 + u2*u2 + u3*u3) + EPS);
        float ar0 = u0*arn, ar1 = u1*arn, ar2 = u2*arn, ar3 = u3*arn;
        if (n == 63) { ar0 = 1.f; ar1 = ar2 = ar3 = 0.f; }

        const float* w = vl[kk];
        float wn = 1.f / (sqrtf(w[0]*w[0] + w[1]*w[1] + w[2]*w[2] + w[3]*w[3]) + EPS);
        float v0 = w[0]*wn, v1 = w[1]*wn, v2 = w[2]*wn, v3 = w[3]*wn;
        if (n == 0) { v0 = 1.f; v1 = v2 = v3 = 0.f; }

        // B[n]: 16 float4, coeff(i,l) = vl_i * ar_l, q = (H00,H01,H10,H11)
        float4 bb[16];
        const float4* Bq = (const float4*)Bw + (size_t)n * 16;
        #pragma unroll
        for (int t = 0; t < 16; ++t) bb[t] = Bq[t];

        const float vv[4] = {v0, v1, v2, v3};
        const float aa[4] = {ar0, ar1, ar2, ar3};
        float H00 = 0.f, H01 = 0.f, H10 = 0.f, H11 = 0.f;
        #pragma unroll
        for (int i = 0; i < 4; ++i) {
            #pragma unroll
            for (int l = 0; l < 4; ++l) {
                const float c = vv[i] * aa[l];
                const float4 q = bb[i*4 + l];
                H00 = fmaf(c, q.x, H00);
                H01 = fmaf(c, q.y, H01);
                H10 = fmaf(c, q.z, H10);
                H11 = fmaf(c, q.w, H11);
            }
        }
        const float rh = sc / (sqrtf(H00*H00 + H01*H01 + H10*H10 + H11*H11) + EPS);
        H00 *= rh; H01 *= rh; H10 *= rh; H11 *= rh;
        if (__builtin_isnan(H00)) H00 = 0.f;
        if (__builtin_isnan(H01)) H01 = 0.f;
        if (__builtin_isnan(H10)) H10 = 0.f;
        if (__builtin_isnan(H11)) H11 = 0.f;
        H00 = fmaxf(H00, 0.f); H01 = fmaxf(H01, 0.f);
        H10 = fmaxf(H10, 0.f); H11 = fmaxf(H11, 0.f);

        yo[2*kk]     = fmaf(H01, xn[kk][1], H00 * xn[kk][0]);
        yo[2*kk + 1] = fmaf(H11, xn[kk][1], H10 * xn[kk][0]);

        if (kk > 0) {   // Ar[n-1] raw = M[n] . u
            float Mm[16];
            build_M(A, n, xn[kk][0], xn[kk][1], Mm);
            const float t0 = Mm[0]*u0  + Mm[1]*u1  + Mm[2]*u2  + Mm[3]*u3;
            const float t1 = Mm[4]*u0  + Mm[5]*u1  + Mm[6]*u2  + Mm[7]*u3;
            const float t2 = Mm[8]*u0  + Mm[9]*u1  + Mm[10]*u2 + Mm[11]*u3;
            const float t3 = Mm[12]*u0 + Mm[13]*u1 + Mm[14]*u2 + Mm[15]*u3;
            u0 = t0; u1 = t1; u2 = t2; u3 = t3;
        }
    }

    ((float4*)yb)[s*2]     = make_float4(yo[0], yo[1], yo[2], yo[3]);
    ((float4*)yb)[s*2 + 1] = make_float4(yo[4], yo[5], yo[6], yo[7]);
}

extern "C" void kernel_launch(void* const* d_in, const int* in_sizes, int n_in,
                              void* d_out, int out_size, void* d_ws, size_t ws_size,
                              hipStream_t stream) {
    const float* x     = (const float*)d_in[0];
    const float* A     = (const float*)d_in[1];
    const float* B     = (const float*)d_in[2];
    const float* scale = (const float*)d_in[3];
    float* yp = (float*)d_out;
    const int batch  = in_sizes[0] / 128;    // 16384
    const int blocks = batch / BPB;          // 1024 blocks x 256 threads
    tdvp_kernel<<<blocks, 256, 0, stream>>>(x, A, B, scale, yp);
}

// Round 4
// 124.747 us; speedup vs baseline: 1.0529x; 1.0529x over previous
//
#include <hip/hip_runtime.h>
#include <math.h>

// TDVP_V2: BATCH=16384 chains, N=64 sites, D=4, DIN=DOUT=2.
// v4: segmented parallel scan with A/B staged in LDS (SoA-over-n).
// Thread = (b, s): b = batch-in-block (16), s = segment of 4 sites (16).
// Grid = 1024 blocks x 256 threads -> 4 blocks/CU (LDS 40 KB), 16 waves/CU.
//   stage   : A (8 KB) + B (16 KB) -> LDS as [element][site] so per-site
//             reads are ds_read_b32 with <=2 addresses/bank (conflict-free).
//   phase 1 : per-thread segment product P_s = M[4s]..M[4s+3], Frobenius-
//             normalized -> sPf (SoA, conflict-free).
//   phase 2 : EVERY thread scans sPf for its own prefix vector
//             (e0^T P_0..P_{s-1}) and suffix vector (P_{s+1}..P_15 e0),
//             normalized each step (direction only; scale cancels in H-norm).
//   phase 3 : 4-site forward walk (vl per site) + backward walk fused with
//             epilogue H = vl.B.ar, norm/nan/relu, y = H.xn. Full fp32.

#define EPS 1e-6f

__device__ __forceinline__ void build_M_lds(const float* __restrict__ sAf,
                                            int n, float xn0, float xn1,
                                            float* Mm) {
    #pragma unroll
    for (int e = 0; e < 16; ++e) {
        const float a0 = sAf[(2 * e) * 64 + n];
        const float a1 = sAf[(2 * e + 1) * 64 + n];
        Mm[e] = fmaf(xn1, a1, xn0 * a0);
    }
}

__global__ __launch_bounds__(256, 4)
void tdvp_kernel(const float* __restrict__ x,
                 const float* __restrict__ A,
                 const float* __restrict__ Bw,
                 const float* __restrict__ scale,
                 float* __restrict__ y)
{
    __shared__ float sAf[32 * 64];    // A[e2][n], e2 = (i*4+j)*2 + i_in
    __shared__ float sBf[64 * 64];    // B[e][n],  e  = i*16 + l*4 + j*2 + k
    __shared__ float sPf[16 * 256];   // P[e][b*16+s]

    const int tid   = threadIdx.x;
    const int b     = tid >> 4;
    const int s     = tid & 15;
    const int batch = blockIdx.x * 16 + b;
    const int n0    = s * 4;

    // ---------------- stage A and B into SoA-over-n LDS ---------------------
    {
        const float4* Aq = (const float4*)A;            // 512 float4 total
        const float4 qa0 = Aq[tid * 2];
        const float4 qa1 = Aq[tid * 2 + 1];
        const float va[8] = {qa0.x, qa0.y, qa0.z, qa0.w,
                             qa1.x, qa1.y, qa1.z, qa1.w};
        const int g = tid * 8;
        #pragma unroll
        for (int j = 0; j < 8; ++j) {
            const int gg = g + j;
            sAf[(gg & 31) * 64 + (gg >> 5)] = va[j];
        }
        const float4* Bq = (const float4*)Bw;           // 1024 float4 total
        #pragma unroll
        for (int t = 0; t < 4; ++t) {
            const float4 qb = Bq[tid * 4 + t];
            const int gb = tid * 16 + t * 4;            // n = gb>>6 = tid>>2
            const int n  = gb >> 6;
            sBf[((gb + 0) & 63) * 64 + n] = qb.x;
            sBf[((gb + 1) & 63) * 64 + n] = qb.y;
            sBf[((gb + 2) & 63) * 64 + n] = qb.z;
            sBf[((gb + 3) & 63) * 64 + n] = qb.w;
        }
    }

    // x for this thread's 4 sites -> normalized xn (overlaps staging)
    const float4 xq0 = ((const float4*)(x + (size_t)batch * 128))[s * 2];
    const float4 xq1 = ((const float4*)(x + (size_t)batch * 128))[s * 2 + 1];
    float xn[4][2];
    {
        const float px[8] = {xq0.x, xq0.y, xq0.z, xq0.w,
                             xq1.x, xq1.y, xq1.z, xq1.w};
        #pragma unroll
        for (int k = 0; k < 4; ++k) {
            const float xx = px[2 * k], xy = px[2 * k + 1];
            const float inr = 1.f / sqrtf(xx * xx + xy * xy);
            xn[k][0] = xx * inr; xn[k][1] = xy * inr;
        }
    }
    __syncthreads();

    // ---------------- phase 1: segment product P = M0.M1.M2.M3 --------------
    {
        float P[16];
        build_M_lds(sAf, n0, xn[0][0], xn[0][1], P);
        #pragma unroll
        for (int k = 1; k < 4; ++k) {
            float Mm[16];
            build_M_lds(sAf, n0 + k, xn[k][0], xn[k][1], Mm);
            float Pn[16];
            #pragma unroll
            for (int i = 0; i < 4; ++i) {
                #pragma unroll
                for (int j = 0; j < 4; ++j) {
                    float acc = P[i*4] * Mm[j];
                    acc = fmaf(P[i*4+1], Mm[4+j],  acc);
                    acc = fmaf(P[i*4+2], Mm[8+j],  acc);
                    acc = fmaf(P[i*4+3], Mm[12+j], acc);
                    Pn[i*4+j] = acc;
                }
            }
            #pragma unroll
            for (int e = 0; e < 16; ++e) P[e] = Pn[e];
        }
        float ss = 0.f;
        #pragma unroll
        for (int e = 0; e < 16; ++e) ss = fmaf(P[e], P[e], ss);
        const float rn = 1.f / (sqrtf(ss) + 1e-30f);
        #pragma unroll
        for (int e = 0; e < 16; ++e) sPf[e * 256 + tid] = P[e] * rn;
    }
    __syncthreads();

    // ---------------- phase 2: per-thread prefix / suffix vector scans ------
    float v0 = 1.f, v1 = 0.f, v2 = 0.f, v3 = 0.f;   // prefix (row) for seg s
    #pragma unroll 1
    for (int t = 0; t < s; ++t) {
        float p[16];
        #pragma unroll
        for (int e = 0; e < 16; ++e) p[e] = sPf[e * 256 + b * 16 + t];
        const float w0 = v0*p[0]  + v1*p[4]  + v2*p[8]   + v3*p[12];
        const float w1 = v0*p[1]  + v1*p[5]  + v2*p[9]   + v3*p[13];
        const float w2 = v0*p[2]  + v1*p[6]  + v2*p[10]  + v3*p[14];
        const float w3 = v0*p[3]  + v1*p[7]  + v2*p[11]  + v3*p[15];
        const float rn = 1.f / (sqrtf(w0*w0 + w1*w1 + w2*w2 + w3*w3) + 1e-30f);
        v0 = w0*rn; v1 = w1*rn; v2 = w2*rn; v3 = w3*rn;
    }
    float u0 = 1.f, u1 = 0.f, u2 = 0.f, u3 = 0.f;   // suffix (col) for seg s
    #pragma unroll 1
    for (int t = 15; t > s; --t) {
        float p[16];
        #pragma unroll
        for (int e = 0; e < 16; ++e) p[e] = sPf[e * 256 + b * 16 + t];
        const float w0 = p[0]*u0  + p[1]*u1  + p[2]*u2  + p[3]*u3;
        const float w1 = p[4]*u0  + p[5]*u1  + p[6]*u2  + p[7]*u3;
        const float w2 = p[8]*u0  + p[9]*u1  + p[10]*u2 + p[11]*u3;
        const float w3 = p[12]*u0 + p[13]*u1 + p[14]*u2 + p[15]*u3;
        const float rn = 1.f / (sqrtf(w0*w0 + w1*w1 + w2*w2 + w3*w3) + 1e-30f);
        u0 = w0*rn; u1 = w1*rn; u2 = w2*rn; u3 = w3*rn;
    }

    // ---------------- phase 3: per-site walks + fused epilogue --------------
    float vl[4][4];
    {
        float a0 = v0, a1 = v1, a2 = v2, a3 = v3;
        #pragma unroll
        for (int k = 0; k < 4; ++k) {
            vl[k][0] = a0; vl[k][1] = a1; vl[k][2] = a2; vl[k][3] = a3;
            if (k == 3) break;
            float Mm[16];
            build_M_lds(sAf, n0 + k, xn[k][0], xn[k][1], Mm);
            const float t0 = a0*Mm[0] + a1*Mm[4] + a2*Mm[8]  + a3*Mm[12];
            const float t1 = a0*Mm[1] + a1*Mm[5] + a2*Mm[9]  + a3*Mm[13];
            const float t2 = a0*Mm[2] + a1*Mm[6] + a2*Mm[10] + a3*Mm[14];
            const float t3 = a0*Mm[3] + a1*Mm[7] + a2*Mm[11] + a3*Mm[15];
            a0 = t0; a1 = t1; a2 = t2; a3 = t3;
        }
    }

    const float sc = scale[0];
    float yo[8];
    #pragma unroll
    for (int kk = 3; kk >= 0; --kk) {
        const int n = n0 + kk;

        const float arn = 1.f / (sqrtf(u0*u0 + u1*u1 + u2*u2 + u3*u3) + EPS);
        float aa[4] = {u0*arn, u1*arn, u2*arn, u3*arn};
        if (n == 63) { aa[0] = 1.f; aa[1] = aa[2] = aa[3] = 0.f; }

        const float* w = vl[kk];
        const float wn = 1.f / (sqrtf(w[0]*w[0] + w[1]*w[1] + w[2]*w[2] + w[3]*w[3]) + EPS);
        float vv[4] = {w[0]*wn, w[1]*wn, w[2]*wn, w[3]*wn};
        if (n == 0) { vv[0] = 1.f; vv[1] = vv[2] = vv[3] = 0.f; }

        float H00 = 0.f, H01 = 0.f, H10 = 0.f, H11 = 0.f;
        #pragma unroll
        for (int i = 0; i < 4; ++i) {
            #pragma unroll
            for (int l = 0; l < 4; ++l) {
                const float c  = vv[i] * aa[l];
                const int   eb = (i * 16 + l * 4) * 64 + n;
                H00 = fmaf(c, sBf[eb],       H00);
                H01 = fmaf(c, sBf[eb + 64],  H01);
                H10 = fmaf(c, sBf[eb + 128], H10);
                H11 = fmaf(c, sBf[eb + 192], H11);
            }
        }
        const float rh = sc / (sqrtf(H00*H00 + H01*H01 + H10*H10 + H11*H11) + EPS);
        H00 *= rh; H01 *= rh; H10 *= rh; H11 *= rh;
        if (__builtin_isnan(H00)) H00 = 0.f;
        if (__builtin_isnan(H01)) H01 = 0.f;
        if (__builtin_isnan(H10)) H10 = 0.f;
        if (__builtin_isnan(H11)) H11 = 0.f;
        H00 = fmaxf(H00, 0.f); H01 = fmaxf(H01, 0.f);
        H10 = fmaxf(H10, 0.f); H11 = fmaxf(H11, 0.f);

        yo[2*kk]     = fmaf(H01, xn[kk][1], H00 * xn[kk][0]);
        yo[2*kk + 1] = fmaf(H11, xn[kk][1], H10 * xn[kk][0]);

        if (kk > 0) {   // u <- M[n] . u  (raw suffix for site n-1)
            float Mm[16];
            build_M_lds(sAf, n, xn[kk][0], xn[kk][1], Mm);
            const float t0 = Mm[0]*u0  + Mm[1]*u1  + Mm[2]*u2  + Mm[3]*u3;
            const float t1 = Mm[4]*u0  + Mm[5]*u1  + Mm[6]*u2  + Mm[7]*u3;
            const float t2 = Mm[8]*u0  + Mm[9]*u1  + Mm[10]*u2 + Mm[11]*u3;
            const float t3 = Mm[12]*u0 + Mm[13]*u1 + Mm[14]*u2 + Mm[15]*u3;
            u0 = t0; u1 = t1; u2 = t2; u3 = t3;
        }
    }

    float4* yq = (float4*)(y + (size_t)batch * 128);
    yq[s*2]     = make_float4(yo[0], yo[1], yo[2], yo[3]);
    yq[s*2 + 1] = make_float4(yo[4], yo[5], yo[6], yo[7]);
}

extern "C" void kernel_launch(void* const* d_in, const int* in_sizes, int n_in,
                              void* d_out, int out_size, void* d_ws, size_t ws_size,
                              hipStream_t stream) {
    const float* x     = (const float*)d_in[0];
    const float* A     = (const float*)d_in[1];
    const float* B     = (const float*)d_in[2];
    const float* scale = (const float*)d_in[3];
    float* yp = (float*)d_out;
    const int batch  = in_sizes[0] / 128;    // 16384
    const int blocks = batch / 16;           // 1024 blocks x 256 threads
    tdvp_kernel<<<blocks, 256, 0, stream>>>(x, A, B, scale, yp);
}

// Round 7
// 87.390 us; speedup vs baseline: 1.5030x; 1.4275x over previous
//
#include <hip/hip_runtime.h>
#include <math.h>

// TDVP_V2: BATCH=16384 chains, N=64 sites, D=4, DIN=DOUT=2.
// v7: segmented parallel scan, 8 threads per chain, block=256 (blocks >256
// threads silently fail to launch in this harness — v5/v6 evidence).
//   bb = tid&31 : batch-in-block (32 chains/block)
//   s  = tid>>5 : segment 0..7 (8 sites each); only 2 distinct s per wave
//                 -> A/B loads are 2-address broadcasts from L1/L2.
//   grid = 512 blocks -> 2048 waves -> 8 waves/CU.
// Phase 1: per-thread segment product P_s = M[8s..8s+7], Frobenius-normalized
//          -> LDS sP[t][e][bb] (fp32, 16 KB; bank = bb%32 -> conflict-free).
// Phase 2: per-thread vector scans over sP (<=7 steps each way, named scalars
//          only inside the divergent-trip loops -> nothing to spill).
//          Normalize each step (direction only; scale cancels in H-norm).
// Phase 3: 8-site forward walk (vl) + backward walk fused with epilogue
//          H = vl.B.ar, norm/nan/relu, y = H.xn. Full fp32.

#define EPS 1e-6f

__device__ __forceinline__ void build_M(const float* __restrict__ A, int n,
                                        float xn0, float xn1, float* Mm) {
    const float4* Aq = (const float4*)A + (size_t)n * 8;
    #pragma unroll
    for (int t = 0; t < 8; ++t) {
        const float4 q = Aq[t];
        Mm[2*t]     = fmaf(xn1, q.y, xn0 * q.x);
        Mm[2*t + 1] = fmaf(xn1, q.w, xn0 * q.z);
    }
}

__global__ __launch_bounds__(256)
void tdvp_kernel(const float* __restrict__ x,
                 const float* __restrict__ A,
                 const float* __restrict__ Bw,
                 const float* __restrict__ scale,
                 float* __restrict__ y)
{
    __shared__ float sP[8 * 16 * 32];   // [t][e][bb]

    const int tid   = threadIdx.x;
    const int bb    = tid & 31;
    const int s     = tid >> 5;         // 0..7
    const int batch = blockIdx.x * 32 + bb;
    const int n0    = s * 8;

    const float* xb = x + (size_t)batch * 128;
    float*       yb = y + (size_t)batch * 128;

    // ---- x for this thread's 8 sites, normalized ------------------------
    float xa[8], xc[8];                 // xn components per site
    {
        const float4* xq = (const float4*)xb;
        #pragma unroll
        for (int q = 0; q < 4; ++q) {
            const float4 v = xq[s * 4 + q];
            const float i0 = 1.f / sqrtf(v.x * v.x + v.y * v.y);
            xa[2*q]   = v.x * i0;  xc[2*q]   = v.y * i0;
            const float i1 = 1.f / sqrtf(v.z * v.z + v.w * v.w);
            xa[2*q+1] = v.z * i1;  xc[2*q+1] = v.w * i1;
        }
    }

    // ---- phase 1: segment product P = M[n0..n0+7] (normalized) ----------
    {
        float P[16];
        build_M(A, n0, xa[0], xc[0], P);
        #pragma unroll
        for (int k = 1; k < 8; ++k) {
            float Mm[16];
            build_M(A, n0 + k, xa[k], xc[k], Mm);
            float Pn[16];
            #pragma unroll
            for (int i = 0; i < 4; ++i) {
                #pragma unroll
                for (int j = 0; j < 4; ++j) {
                    float acc = P[i*4] * Mm[j];
                    acc = fmaf(P[i*4+1], Mm[4+j],  acc);
                    acc = fmaf(P[i*4+2], Mm[8+j],  acc);
                    acc = fmaf(P[i*4+3], Mm[12+j], acc);
                    Pn[i*4+j] = acc;
                }
            }
            #pragma unroll
            for (int e = 0; e < 16; ++e) P[e] = Pn[e];
        }
        float ss = 0.f;
        #pragma unroll
        for (int e = 0; e < 16; ++e) ss = fmaf(P[e], P[e], ss);
        const float rn = 1.f / (sqrtf(ss) + 1e-30f);
        #pragma unroll
        for (int e = 0; e < 16; ++e)
            sP[s * 512 + e * 32 + bb] = P[e] * rn;
    }
    __syncthreads();

    // ---- phase 2: per-thread prefix / suffix vector scans ---------------
    // prefix: v = e0^T P_0 .. P_{s-1}   (row vector, <=7 steps)
    float v0 = 1.f, v1 = 0.f, v2 = 0.f, v3 = 0.f;
    #pragma unroll 1
    for (int t = 0; t < s; ++t) {
        const float* pp = &sP[t * 512 + bb];
        const float p0  = pp[0],      p1  = pp[32],     p2  = pp[64],     p3  = pp[96];
        const float p4  = pp[128],    p5  = pp[160],    p6  = pp[192],    p7  = pp[224];
        const float p8  = pp[256],    p9  = pp[288],    p10 = pp[320],    p11 = pp[352];
        const float p12 = pp[384],    p13 = pp[416],    p14 = pp[448],    p15 = pp[480];
        const float w0 = v0*p0 + v1*p4 + v2*p8  + v3*p12;
        const float w1 = v0*p1 + v1*p5 + v2*p9  + v3*p13;
        const float w2 = v0*p2 + v1*p6 + v2*p10 + v3*p14;
        const float w3 = v0*p3 + v1*p7 + v2*p11 + v3*p15;
        const float rn = 1.f / (sqrtf(w0*w0 + w1*w1 + w2*w2 + w3*w3) + 1e-30f);
        v0 = w0*rn; v1 = w1*rn; v2 = w2*rn; v3 = w3*rn;
    }
    // suffix: u = P_{s+1} .. P_7 e0     (col vector, <=7 steps)
    float u0 = 1.f, u1 = 0.f, u2 = 0.f, u3 = 0.f;
    #pragma unroll 1
    for (int t = 7; t > s; --t) {
        const float* pp = &sP[t * 512 + bb];
        const float p0  = pp[0],      p1  = pp[32],     p2  = pp[64],     p3  = pp[96];
        const float p4  = pp[128],    p5  = pp[160],    p6  = pp[192],    p7  = pp[224];
        const float p8  = pp[256],    p9  = pp[288],    p10 = pp[320],    p11 = pp[352];
        const float p12 = pp[384],    p13 = pp[416],    p14 = pp[448],    p15 = pp[480];
        const float w0 = p0*u0  + p1*u1  + p2*u2  + p3*u3;
        const float w1 = p4*u0  + p5*u1  + p6*u2  + p7*u3;
        const float w2 = p8*u0  + p9*u1  + p10*u2 + p11*u3;
        const float w3 = p12*u0 + p13*u1 + p14*u2 + p15*u3;
        const float rn = 1.f / (sqrtf(w0*w0 + w1*w1 + w2*w2 + w3*w3) + 1e-30f);
        u0 = w0*rn; u1 = w1*rn; u2 = w2*rn; u3 = w3*rn;
    }

    // ---- phase 3a: forward walk, store vl per site (static arrays) ------
    float vlA[8], vlB[8], vlC[8], vlD[8];
    {
        float a0 = v0, a1 = v1, a2 = v2, a3 = v3;
        #pragma unroll
        for (int k = 0; k < 8; ++k) {
            vlA[k] = a0; vlB[k] = a1; vlC[k] = a2; vlD[k] = a3;
            if (k == 7) break;
            float Mm[16];
            build_M(A, n0 + k, xa[k], xc[k], Mm);
            const float t0 = a0*Mm[0] + a1*Mm[4] + a2*Mm[8]  + a3*Mm[12];
            const float t1 = a0*Mm[1] + a1*Mm[5] + a2*Mm[9]  + a3*Mm[13];
            const float t2 = a0*Mm[2] + a1*Mm[6] + a2*Mm[10] + a3*Mm[14];
            const float t3 = a0*Mm[3] + a1*Mm[7] + a2*Mm[11] + a3*Mm[15];
            a0 = t0; a1 = t1; a2 = t2; a3 = t3;
        }
    }

    // ---- phase 3b: backward walk + fused epilogue -----------------------
    const float sc = scale[0];
    #pragma unroll
    for (int kk = 7; kk >= 0; --kk) {
        const int n = n0 + kk;

        const float arn = 1.f / (sqrtf(u0*u0 + u1*u1 + u2*u2 + u3*u3) + EPS);
        float aa0 = u0*arn, aa1 = u1*arn, aa2 = u2*arn, aa3 = u3*arn;
        if (n == 63) { aa0 = 1.f; aa1 = aa2 = aa3 = 0.f; }

        const float wn = 1.f / (sqrtf(vlA[kk]*vlA[kk] + vlB[kk]*vlB[kk] +
                                      vlC[kk]*vlC[kk] + vlD[kk]*vlD[kk]) + EPS);
        float vv0 = vlA[kk]*wn, vv1 = vlB[kk]*wn, vv2 = vlC[kk]*wn, vv3 = vlD[kk]*wn;
        if (n == 0) { vv0 = 1.f; vv1 = vv2 = vv3 = 0.f; }

        const float vv[4] = {vv0, vv1, vv2, vv3};
        const float aa[4] = {aa0, aa1, aa2, aa3};
        const float4* Bq = (const float4*)Bw + (size_t)n * 16;
        float H00 = 0.f, H01 = 0.f, H10 = 0.f, H11 = 0.f;
        #pragma unroll
        for (int i = 0; i < 4; ++i) {
            #pragma unroll
            for (int l = 0; l < 4; ++l) {
                const float  c = vv[i] * aa[l];
                const float4 q = Bq[i*4 + l];
                H00 = fmaf(c, q.x, H00);
                H01 = fmaf(c, q.y, H01);
                H10 = fmaf(c, q.z, H10);
                H11 = fmaf(c, q.w, H11);
            }
        }
        const float rh = sc / (sqrtf(H00*H00 + H01*H01 + H10*H10 + H11*H11) + EPS);
        H00 *= rh; H01 *= rh; H10 *= rh; H11 *= rh;
        if (__builtin_isnan(H00)) H00 = 0.f;
        if (__builtin_isnan(H01)) H01 = 0.f;
        if (__builtin_isnan(H10)) H10 = 0.f;
        if (__builtin_isnan(H11)) H11 = 0.f;
        H00 = fmaxf(H00, 0.f); H01 = fmaxf(H01, 0.f);
        H10 = fmaxf(H10, 0.f); H11 = fmaxf(H11, 0.f);

        float2 yo;
        yo.x = fmaf(H01, xc[kk], H00 * xa[kk]);
        yo.y = fmaf(H11, xc[kk], H10 * xa[kk]);
        *(float2*)(yb + n * 2) = yo;

        if (kk > 0) {   // u <- M[n].u  (raw suffix for site n-1)
            float Mm[16];
            build_M(A, n, xa[kk], xc[kk], Mm);
            const float t0 = Mm[0]*u0  + Mm[1]*u1  + Mm[2]*u2  + Mm[3]*u3;
            const float t1 = Mm[4]*u0  + Mm[5]*u1  + Mm[6]*u2  + Mm[7]*u3;
            const float t2 = Mm[8]*u0  + Mm[9]*u1  + Mm[10]*u2 + Mm[11]*u3;
            const float t3 = Mm[12]*u0 + Mm[13]*u1 + Mm[14]*u2 + Mm[15]*u3;
            u0 = t0; u1 = t1; u2 = t2; u3 = t3;
        }
    }
}

extern "C" void kernel_launch(void* const* d_in, const int* in_sizes, int n_in,
                              void* d_out, int out_size, void* d_ws, size_t ws_size,
                              hipStream_t stream) {
    const float* x     = (const float*)d_in[0];
    const float* A     = (const float*)d_in[1];
    const float* B     = (const float*)d_in[2];
    const float* scale = (const float*)d_in[3];
    float* yp = (float*)d_out;
    const int batch  = in_sizes[0] / 128;    // 16384
    const int blocks = batch / 32;           // 512 blocks x 256 threads
    tdvp_kernel<<<blocks, 256, 0, stream>>>(x, A, B, scale, yp);
}

// Round 9
// 84.542 us; speedup vs baseline: 1.5536x; 1.0337x over previous
//
#include <hip/hip_runtime.h>
#include <math.h>

// TDVP_V2: BATCH=16384 chains, N=64 sites, D=4, DIN=DOUT=2.
// v9 = v7 (proven) + coalesced x/y through one reused LDS buffer.
//   bb = tid&31 : batch-in-block (32 chains/block)
//   s  = tid>>5 : segment 0..7 (8 sites each); 2 distinct s per wave.
//   grid = 512 blocks x 256 threads -> 2 blocks/CU, 8 waves/CU.
// NEW vs v7 (the only change): x is block-loaded fully coalesced (float4,
// 16 B/lane) into sXY (stride 130 -> <=2 addr/bank on all accesses), read
// per-thread as float2; y is staged per-site into the SAME buffer (x is in
// registers before the phase-1 barrier -> reuse is race-free) and written
// out fully coalesced as float4. v7 wrote float2 at 512-B chain stride:
// 32+ cache lines per wave-store (~8x L2 write-transaction amplification).
// Phases 1-3 are v7 verbatim:
//   1: per-thread 8-site product P_s (Frobenius-normalized) -> sP fp32.
//   2: per-thread prefix/suffix vector scans over sP (<=7 steps each,
//      normalized each step; scale cancels in the H-normalization).
//   3: forward walk (vl per site) + backward walk fused with epilogue
//      H = vl.B.ar, norm/nan/relu, y = H.xn.

#define EPS 1e-6f

__device__ __forceinline__ void build_M(const float* __restrict__ A, int n,
                                        float xn0, float xn1, float* Mm) {
    const float4* Aq = (const float4*)A + (size_t)n * 8;
    #pragma unroll
    for (int t = 0; t < 8; ++t) {
        const float4 q = Aq[t];
        Mm[2*t]     = fmaf(xn1, q.y, xn0 * q.x);
        Mm[2*t + 1] = fmaf(xn1, q.w, xn0 * q.z);
    }
}

__global__ __launch_bounds__(256)
void tdvp_kernel(const float* __restrict__ x,
                 const float* __restrict__ A,
                 const float* __restrict__ Bw,
                 const float* __restrict__ scale,
                 float* __restrict__ y)
{
    __shared__ float sP[8 * 16 * 32];   // [t][e][bb]      16 KB
    __shared__ float sXY[32 * 130];     // [chain][2*site] 16.6 KB, pad stride

    const int tid   = threadIdx.x;
    const int bb    = tid & 31;
    const int s     = tid >> 5;         // 0..7

    // ---- stage x: fully coalesced block load -> sXY ----------------------
    {
        const float4* xg = (const float4*)x + (size_t)blockIdx.x * 1024;
        #pragma unroll
        for (int it = 0; it < 4; ++it) {
            const int g = it * 256 + tid;
            const float4 v = xg[g];
            const int c = g >> 5, f = (g & 31) * 4;
            *(float2*)&sXY[c * 130 + f]     = make_float2(v.x, v.y);
            *(float2*)&sXY[c * 130 + f + 2] = make_float2(v.z, v.w);
        }
    }
    __syncthreads();

    // ---- my 8 sites from LDS, normalized --------------------------------
    const int n0 = s * 8;
    float xa[8], xc[8];
    #pragma unroll
    for (int k = 0; k < 8; ++k) {
        const float2 v = *(const float2*)&sXY[bb * 130 + s * 16 + 2 * k];
        const float inr = 1.f / sqrtf(v.x * v.x + v.y * v.y);
        xa[k] = v.x * inr; xc[k] = v.y * inr;
    }

    // ---- phase 1: segment product P = M[n0..n0+7] (normalized) ----------
    {
        float P[16];
        build_M(A, n0, xa[0], xc[0], P);
        #pragma unroll
        for (int k = 1; k < 8; ++k) {
            float Mm[16];
            build_M(A, n0 + k, xa[k], xc[k], Mm);
            float Pn[16];
            #pragma unroll
            for (int i = 0; i < 4; ++i) {
                #pragma unroll
                for (int j = 0; j < 4; ++j) {
                    float acc = P[i*4] * Mm[j];
                    acc = fmaf(P[i*4+1], Mm[4+j],  acc);
                    acc = fmaf(P[i*4+2], Mm[8+j],  acc);
                    acc = fmaf(P[i*4+3], Mm[12+j], acc);
                    Pn[i*4+j] = acc;
                }
            }
            #pragma unroll
            for (int e = 0; e < 16; ++e) P[e] = Pn[e];
        }
        float ss = 0.f;
        #pragma unroll
        for (int e = 0; e < 16; ++e) ss = fmaf(P[e], P[e], ss);
        const float rn = 1.f / (sqrtf(ss) + 1e-30f);
        #pragma unroll
        for (int e = 0; e < 16; ++e)
            sP[s * 512 + e * 32 + bb] = P[e] * rn;
    }
    __syncthreads();

    // ---- phase 2: per-thread prefix / suffix vector scans ---------------
    float v0 = 1.f, v1 = 0.f, v2 = 0.f, v3 = 0.f;
    #pragma unroll 1
    for (int t = 0; t < s; ++t) {
        const float* pp = &sP[t * 512 + bb];
        const float p0  = pp[0],      p1  = pp[32],     p2  = pp[64],     p3  = pp[96];
        const float p4  = pp[128],    p5  = pp[160],    p6  = pp[192],    p7  = pp[224];
        const float p8  = pp[256],    p9  = pp[288],    p10 = pp[320],    p11 = pp[352];
        const float p12 = pp[384],    p13 = pp[416],    p14 = pp[448],    p15 = pp[480];
        const float w0 = v0*p0 + v1*p4 + v2*p8  + v3*p12;
        const float w1 = v0*p1 + v1*p5 + v2*p9  + v3*p13;
        const float w2 = v0*p2 + v1*p6 + v2*p10 + v3*p14;
        const float w3 = v0*p3 + v1*p7 + v2*p11 + v3*p15;
        const float rn = 1.f / (sqrtf(w0*w0 + w1*w1 + w2*w2 + w3*w3) + 1e-30f);
        v0 = w0*rn; v1 = w1*rn; v2 = w2*rn; v3 = w3*rn;
    }
    float u0 = 1.f, u1 = 0.f, u2 = 0.f, u3 = 0.f;
    #pragma unroll 1
    for (int t = 7; t > s; --t) {
        const float* pp = &sP[t * 512 + bb];
        const float p0  = pp[0],      p1  = pp[32],     p2  = pp[64],     p3  = pp[96];
        const float p4  = pp[128],    p5  = pp[160],    p6  = pp[192],    p7  = pp[224];
        const float p8  = pp[256],    p9  = pp[288],    p10 = pp[320],    p11 = pp[352];
        const float p12 = pp[384],    p13 = pp[416],    p14 = pp[448],    p15 = pp[480];
        const float w0 = p0*u0  + p1*u1  + p2*u2  + p3*u3;
        const float w1 = p4*u0  + p5*u1  + p6*u2  + p7*u3;
        const float w2 = p8*u0  + p9*u1  + p10*u2 + p11*u3;
        const float w3 = p12*u0 + p13*u1 + p14*u2 + p15*u3;
        const float rn = 1.f / (sqrtf(w0*w0 + w1*w1 + w2*w2 + w3*w3) + 1e-30f);
        u0 = w0*rn; u1 = w1*rn; u2 = w2*rn; u3 = w3*rn;
    }

    // ---- phase 3a: forward walk, store vl per site -----------------------
    float vlA[8], vlB[8], vlC[8], vlD[8];
    {
        float a0 = v0, a1 = v1, a2 = v2, a3 = v3;
        #pragma unroll
        for (int k = 0; k < 8; ++k) {
            vlA[k] = a0; vlB[k] = a1; vlC[k] = a2; vlD[k] = a3;
            if (k == 7) break;
            float Mm[16];
            build_M(A, n0 + k, xa[k], xc[k], Mm);
            const float t0 = a0*Mm[0] + a1*Mm[4] + a2*Mm[8]  + a3*Mm[12];
            const float t1 = a0*Mm[1] + a1*Mm[5] + a2*Mm[9]  + a3*Mm[13];
            const float t2 = a0*Mm[2] + a1*Mm[6] + a2*Mm[10] + a3*Mm[14];
            const float t3 = a0*Mm[3] + a1*Mm[7] + a2*Mm[11] + a3*Mm[15];
            a0 = t0; a1 = t1; a2 = t2; a3 = t3;
        }
    }

    // ---- phase 3b: backward walk + fused epilogue -> sXY -----------------
    const float sc = scale[0];
    #pragma unroll
    for (int kk = 7; kk >= 0; --kk) {
        const int n = n0 + kk;

        const float arn = 1.f / (sqrtf(u0*u0 + u1*u1 + u2*u2 + u3*u3) + EPS);
        float aa0 = u0*arn, aa1 = u1*arn, aa2 = u2*arn, aa3 = u3*arn;
        if (n == 63) { aa0 = 1.f; aa1 = aa2 = aa3 = 0.f; }

        const float wn = 1.f / (sqrtf(vlA[kk]*vlA[kk] + vlB[kk]*vlB[kk] +
                                      vlC[kk]*vlC[kk] + vlD[kk]*vlD[kk]) + EPS);
        float vv0 = vlA[kk]*wn, vv1 = vlB[kk]*wn, vv2 = vlC[kk]*wn, vv3 = vlD[kk]*wn;
        if (n == 0) { vv0 = 1.f; vv1 = vv2 = vv3 = 0.f; }

        const float vv[4] = {vv0, vv1, vv2, vv3};
        const float aa[4] = {aa0, aa1, aa2, aa3};
        const float4* Bq = (const float4*)Bw + (size_t)n * 16;
        float H00 = 0.f, H01 = 0.f, H10 = 0.f, H11 = 0.f;
        #pragma unroll
        for (int i = 0; i < 4; ++i) {
            #pragma unroll
            for (int l = 0; l < 4; ++l) {
                const float  c = vv[i] * aa[l];
                const float4 q = Bq[i*4 + l];
                H00 = fmaf(c, q.x, H00);
                H01 = fmaf(c, q.y, H01);
                H10 = fmaf(c, q.z, H10);
                H11 = fmaf(c, q.w, H11);
            }
        }
        const float rh = sc / (sqrtf(H00*H00 + H01*H01 + H10*H10 + H11*H11) + EPS);
        H00 *= rh; H01 *= rh; H10 *= rh; H11 *= rh;
        if (__builtin_isnan(H00)) H00 = 0.f;
        if (__builtin_isnan(H01)) H01 = 0.f;
        if (__builtin_isnan(H10)) H10 = 0.f;
        if (__builtin_isnan(H11)) H11 = 0.f;
        H00 = fmaxf(H00, 0.f); H01 = fmaxf(H01, 0.f);
        H10 = fmaxf(H10, 0.f); H11 = fmaxf(H11, 0.f);

        float2 yo;
        yo.x = fmaf(H01, xc[kk], H00 * xa[kk]);
        yo.y = fmaf(H11, xc[kk], H10 * xa[kk]);
        *(float2*)&sXY[bb * 130 + 2 * n] = yo;

        if (kk > 0) {   // u <- M[n].u  (raw suffix for site n-1)
            float Mm[16];
            build_M(A, n, xa[kk], xc[kk], Mm);
            const float t0 = Mm[0]*u0  + Mm[1]*u1  + Mm[2]*u2  + Mm[3]*u3;
            const float t1 = Mm[4]*u0  + Mm[5]*u1  + Mm[6]*u2  + Mm[7]*u3;
            const float t2 = Mm[8]*u0  + Mm[9]*u1  + Mm[10]*u2 + Mm[11]*u3;
            const float t3 = Mm[12]*u0 + Mm[13]*u1 + Mm[14]*u2 + Mm[15]*u3;
            u0 = t0; u1 = t1; u2 = t2; u3 = t3;
        }
    }
    __syncthreads();

    // ---- y out: fully coalesced float4 stores ----------------------------
    {
        float4* yg = (float4*)y + (size_t)blockIdx.x * 1024;
        #pragma unroll
        for (int it = 0; it < 4; ++it) {
            const int g = it * 256 + tid;
            const int c = g >> 5, f = (g & 31) * 4;
            const float2 a = *(const float2*)&sXY[c * 130 + f];
            const float2 b = *(const float2*)&sXY[c * 130 + f + 2];
            yg[g] = make_float4(a.x, a.y, b.x, b.y);
        }
    }
}

extern "C" void kernel_launch(void* const* d_in, const int* in_sizes, int n_in,
                              void* d_out, int out_size, void* d_ws, size_t ws_size,
                              hipStream_t stream) {
    const float* x     = (const float*)d_in[0];
    const float* A     = (const float*)d_in[1];
    const float* B     = (const float*)d_in[2];
    const float* scale = (const float*)d_in[3];
    float* yp = (float*)d_out;
    const int batch  = in_sizes[0] / 128;    // 16384
    const int blocks = batch / 32;           // 512 blocks x 256 threads
    tdvp_kernel<<<blocks, 256, 0, stream>>>(x, A, B, scale, yp);
}

// Round 10
// 82.349 us; speedup vs baseline: 1.5950x; 1.0266x over previous
//
#include <hip/hip_runtime.h>
#include <math.h>

// TDVP_V2: BATCH=16384 chains, N=64 sites, D=4, DIN=DOUT=2.
// v10 = v9 + all 8 per-site M matrices cached in registers (128 VGPRs).
// v9 called build_M 22x/thread (8 phase-1 + 7 forward walk + 7 backward
// walk): 448 redundant VALU + 112 redundant float4 loads per thread. With
// only 2 waves/SIMD (grid-limited), VGPR headroom to ~256 is free — spend
// it. B loads chunked (8 float4 live at a time) to stay under ~240 VGPR.
//   bb = tid&31 : batch-in-block (32 chains/block)
//   s  = tid>>5 : segment 0..7 (8 sites each); 2 distinct s per wave.
//   grid = 512 blocks x 256 threads -> 2 blocks/CU, 8 waves/CU.
// x in / y out fully coalesced through reused LDS buffer (v9-proven).
// Phases:
//   1: build M[0..7] once -> registers; chain product P (normalized) -> sP.
//   2: per-thread prefix/suffix vector scans over sP (<=7 steps each,
//      normalized; scale cancels in the H-normalization).
//   3a: forward walk (vl per site) using cached M.
//   3b: backward walk + epilogue H = vl.B.ar, norm/nan/relu, y = H.xn,
//       using cached M.

#define EPS 1e-6f

__global__ __launch_bounds__(256)
void tdvp_kernel(const float* __restrict__ x,
                 const float* __restrict__ A,
                 const float* __restrict__ Bw,
                 const float* __restrict__ scale,
                 float* __restrict__ y)
{
    __shared__ float sP[8 * 16 * 32];   // [t][e][bb]      16 KB
    __shared__ float sXY[32 * 130];     // [chain][2*site] 16.6 KB, pad stride

    const int tid   = threadIdx.x;
    const int bb    = tid & 31;
    const int s     = tid >> 5;         // 0..7

    // ---- stage x: fully coalesced block load -> sXY ----------------------
    {
        const float4* xg = (const float4*)x + (size_t)blockIdx.x * 1024;
        #pragma unroll
        for (int it = 0; it < 4; ++it) {
            const int g = it * 256 + tid;
            const float4 v = xg[g];
            const int c = g >> 5, f = (g & 31) * 4;
            *(float2*)&sXY[c * 130 + f]     = make_float2(v.x, v.y);
            *(float2*)&sXY[c * 130 + f + 2] = make_float2(v.z, v.w);
        }
    }
    __syncthreads();

    // ---- my 8 sites from LDS, normalized --------------------------------
    const int n0 = s * 8;
    float xa[8], xc[8];
    #pragma unroll
    for (int k = 0; k < 8; ++k) {
        const float2 v = *(const float2*)&sXY[bb * 130 + s * 16 + 2 * k];
        const float inr = 1.f / sqrtf(v.x * v.x + v.y * v.y);
        xa[k] = v.x * inr; xc[k] = v.y * inr;
    }

    // ---- build all 8 M matrices ONCE into registers ----------------------
    float M[8][16];
    #pragma unroll
    for (int k = 0; k < 8; ++k) {
        const float4* Aq = (const float4*)A + (size_t)(n0 + k) * 8;
        #pragma unroll
        for (int t = 0; t < 8; ++t) {
            const float4 q = Aq[t];
            M[k][2*t]     = fmaf(xc[k], q.y, xa[k] * q.x);
            M[k][2*t + 1] = fmaf(xc[k], q.w, xa[k] * q.z);
        }
    }

    // ---- phase 1: segment product P = M[0]..M[7] (normalized) -> sP ------
    {
        float P[16];
        #pragma unroll
        for (int e = 0; e < 16; ++e) P[e] = M[0][e];
        #pragma unroll
        for (int k = 1; k < 8; ++k) {
            float Pn[16];
            #pragma unroll
            for (int i = 0; i < 4; ++i) {
                #pragma unroll
                for (int j = 0; j < 4; ++j) {
                    float acc = P[i*4] * M[k][j];
                    acc = fmaf(P[i*4+1], M[k][4+j],  acc);
                    acc = fmaf(P[i*4+2], M[k][8+j],  acc);
                    acc = fmaf(P[i*4+3], M[k][12+j], acc);
                    Pn[i*4+j] = acc;
                }
            }
            #pragma unroll
            for (int e = 0; e < 16; ++e) P[e] = Pn[e];
        }
        float ss = 0.f;
        #pragma unroll
        for (int e = 0; e < 16; ++e) ss = fmaf(P[e], P[e], ss);
        const float rn = 1.f / (sqrtf(ss) + 1e-30f);
        #pragma unroll
        for (int e = 0; e < 16; ++e)
            sP[s * 512 + e * 32 + bb] = P[e] * rn;
    }
    __syncthreads();

    // ---- phase 2: per-thread prefix / suffix vector scans ---------------
    float v0 = 1.f, v1 = 0.f, v2 = 0.f, v3 = 0.f;
    #pragma unroll 1
    for (int t = 0; t < s; ++t) {
        const float* pp = &sP[t * 512 + bb];
        const float p0  = pp[0],      p1  = pp[32],     p2  = pp[64],     p3  = pp[96];
        const float p4  = pp[128],    p5  = pp[160],    p6  = pp[192],    p7  = pp[224];
        const float p8  = pp[256],    p9  = pp[288],    p10 = pp[320],    p11 = pp[352];
        const float p12 = pp[384],    p13 = pp[416],    p14 = pp[448],    p15 = pp[480];
        const float w0 = v0*p0 + v1*p4 + v2*p8  + v3*p12;
        const float w1 = v0*p1 + v1*p5 + v2*p9  + v3*p13;
        const float w2 = v0*p2 + v1*p6 + v2*p10 + v3*p14;
        const float w3 = v0*p3 + v1*p7 + v2*p11 + v3*p15;
        const float rn = 1.f / (sqrtf(w0*w0 + w1*w1 + w2*w2 + w3*w3) + 1e-30f);
        v0 = w0*rn; v1 = w1*rn; v2 = w2*rn; v3 = w3*rn;
    }
    float u0 = 1.f, u1 = 0.f, u2 = 0.f, u3 = 0.f;
    #pragma unroll 1
    for (int t = 7; t > s; --t) {
        const float* pp = &sP[t * 512 + bb];
        const float p0  = pp[0],      p1  = pp[32],     p2  = pp[64],     p3  = pp[96];
        const float p4  = pp[128],    p5  = pp[160],    p6  = pp[192],    p7  = pp[224];
        const float p8  = pp[256],    p9  = pp[288],    p10 = pp[320],    p11 = pp[352];
        const float p12 = pp[384],    p13 = pp[416],    p14 = pp[448],    p15 = pp[480];
        const float w0 = p0*u0  + p1*u1  + p2*u2  + p3*u3;
        const float w1 = p4*u0  + p5*u1  + p6*u2  + p7*u3;
        const float w2 = p8*u0  + p9*u1  + p10*u2 + p11*u3;
        const float w3 = p12*u0 + p13*u1 + p14*u2 + p15*u3;
        const float rn = 1.f / (sqrtf(w0*w0 + w1*w1 + w2*w2 + w3*w3) + 1e-30f);
        u0 = w0*rn; u1 = w1*rn; u2 = w2*rn; u3 = w3*rn;
    }

    // ---- phase 3a: forward walk, store vl per site (cached M) ------------
    float vlA[8], vlB[8], vlC[8], vlD[8];
    {
        float a0 = v0, a1 = v1, a2 = v2, a3 = v3;
        #pragma unroll
        for (int k = 0; k < 8; ++k) {
            vlA[k] = a0; vlB[k] = a1; vlC[k] = a2; vlD[k] = a3;
            if (k == 7) break;
            const float t0 = a0*M[k][0] + a1*M[k][4] + a2*M[k][8]  + a3*M[k][12];
            const float t1 = a0*M[k][1] + a1*M[k][5] + a2*M[k][9]  + a3*M[k][13];
            const float t2 = a0*M[k][2] + a1*M[k][6] + a2*M[k][10] + a3*M[k][14];
            const float t3 = a0*M[k][3] + a1*M[k][7] + a2*M[k][11] + a3*M[k][15];
            a0 = t0; a1 = t1; a2 = t2; a3 = t3;
        }
    }

    // ---- phase 3b: backward walk + fused epilogue (cached M) -> sXY ------
    const float sc = scale[0];
    #pragma unroll
    for (int kk = 7; kk >= 0; --kk) {
        const int n = n0 + kk;

        const float arn = 1.f / (sqrtf(u0*u0 + u1*u1 + u2*u2 + u3*u3) + EPS);
        float aa0 = u0*arn, aa1 = u1*arn, aa2 = u2*arn, aa3 = u3*arn;
        if (n == 63) { aa0 = 1.f; aa1 = aa2 = aa3 = 0.f; }

        const float wn = 1.f / (sqrtf(vlA[kk]*vlA[kk] + vlB[kk]*vlB[kk] +
                                      vlC[kk]*vlC[kk] + vlD[kk]*vlD[kk]) + EPS);
        float vv0 = vlA[kk]*wn, vv1 = vlB[kk]*wn, vv2 = vlC[kk]*wn, vv3 = vlD[kk]*wn;
        if (n == 0) { vv0 = 1.f; vv1 = vv2 = vv3 = 0.f; }

        const float vv[4] = {vv0, vv1, vv2, vv3};
        const float aa[4] = {aa0, aa1, aa2, aa3};
        const float4* Bq = (const float4*)Bw + (size_t)n * 16;
        float H00 = 0.f, H01 = 0.f, H10 = 0.f, H11 = 0.f;
        #pragma unroll
        for (int half = 0; half < 2; ++half) {       // chunk B: 8 float4 live
            float4 bq[8];
            #pragma unroll
            for (int t = 0; t < 8; ++t) bq[t] = Bq[half * 8 + t];
            #pragma unroll
            for (int i2 = 0; i2 < 2; ++i2) {
                const int i = half * 2 + i2;
                #pragma unroll
                for (int l = 0; l < 4; ++l) {
                    const float  c = vv[i] * aa[l];
                    const float4 q = bq[i2 * 4 + l];
                    H00 = fmaf(c, q.x, H00);
                    H01 = fmaf(c, q.y, H01);
                    H10 = fmaf(c, q.z, H10);
                    H11 = fmaf(c, q.w, H11);
                }
            }
        }
        const float rh = sc / (sqrtf(H00*H00 + H01*H01 + H10*H10 + H11*H11) + EPS);
        H00 *= rh; H01 *= rh; H10 *= rh; H11 *= rh;
        if (__builtin_isnan(H00)) H00 = 0.f;
        if (__builtin_isnan(H01)) H01 = 0.f;
        if (__builtin_isnan(H10)) H10 = 0.f;
        if (__builtin_isnan(H11)) H11 = 0.f;
        H00 = fmaxf(H00, 0.f); H01 = fmaxf(H01, 0.f);
        H10 = fmaxf(H10, 0.f); H11 = fmaxf(H11, 0.f);

        float2 yo;
        yo.x = fmaf(H01, xc[kk], H00 * xa[kk]);
        yo.y = fmaf(H11, xc[kk], H10 * xa[kk]);
        *(float2*)&sXY[bb * 130 + 2 * n] = yo;

        if (kk > 0) {   // u <- M[kk].u  (raw suffix for site n-1)
            const float t0 = M[kk][0]*u0  + M[kk][1]*u1  + M[kk][2]*u2  + M[kk][3]*u3;
            const float t1 = M[kk][4]*u0  + M[kk][5]*u1  + M[kk][6]*u2  + M[kk][7]*u3;
            const float t2 = M[kk][8]*u0  + M[kk][9]*u1  + M[kk][10]*u2 + M[kk][11]*u3;
            const float t3 = M[kk][12]*u0 + M[kk][13]*u1 + M[kk][14]*u2 + M[kk][15]*u3;
            u0 = t0; u1 = t1; u2 = t2; u3 = t3;
        }
    }
    __syncthreads();

    // ---- y out: fully coalesced float4 stores ----------------------------
    {
        float4* yg = (float4*)y + (size_t)blockIdx.x * 1024;
        #pragma unroll
        for (int it = 0; it < 4; ++it) {
            const int g = it * 256 + tid;
            const int c = g >> 5, f = (g & 31) * 4;
            const float2 a = *(const float2*)&sXY[c * 130 + f];
            const float2 b = *(const float2*)&sXY[c * 130 + f + 2];
            yg[g] = make_float4(a.x, a.y, b.x, b.y);
        }
    }
}

extern "C" void kernel_launch(void* const* d_in, const int* in_sizes, int n_in,
                              void* d_out, int out_size, void* d_ws, size_t ws_size,
                              hipStream_t stream) {
    const float* x     = (const float*)d_in[0];
    const float* A     = (const float*)d_in[1];
    const float* B     = (const float*)d_in[2];
    const float* scale = (const float*)d_in[3];
    float* yp = (float*)d_out;
    const int batch  = in_sizes[0] / 128;    // 16384
    const int blocks = batch / 32;           // 512 blocks x 256 threads
    tdvp_kernel<<<blocks, 256, 0, stream>>>(x, A, B, scale, yp);
}